// Round 10
// baseline (254.965 us; speedup 1.0000x reference)
//
#include <hip/hip_runtime.h>
#include <hip/hip_bf16.h>
#include <stdint.h>

// MoE (E=16, D=1024, H=2048, K=2, T=2048), routed bf16-MFMA.
// R10: ALL-LINEAR-STREAM design. Every hot load is a contiguous stream:
//  - shuffle_w: f32 W -> bf16 fragment-order Wt via LDS bounce (linear read,
//    linear write).
//  - xshuffle: acts -> fragment layout in routed-slot order (tiles padded to
//    256-aligned slot space) -> GEMM act loads are linear.
//  - moe_flat: pure register GEMM, 6 linear bf16 streams per wave, no LDS,
//    no barriers, no gathers. GEMM1 writes h directly in fragment layout.

#define E_ 16
#define D_ 1024
#define H_ 2048
#define K_ 2
#define T_ 2048
#define NP_ (T_ * K_)     // 4096 token-expert pairs
#define MTS_ 32           // max 256-slot tiles (sum ceil(ne/256) <= 32)
#define SGMAX_ 512        // max slot-groups (8192 padded slots / 16)

using short8 = __attribute__((ext_vector_type(8))) short;
using f32x4  = __attribute__((ext_vector_type(4))) float;

__device__ __forceinline__ unsigned short f2bf(float f) {
  union { float f; unsigned u; } x; x.f = f;
  unsigned r = x.u + 0x7fffu + ((x.u >> 16) & 1u);   // RNE
  return (unsigned short)(r >> 16);
}

// gelu(tanh approx) = x * sigmoid(1.595769...*(x + 0.044715 x^3))
__device__ __forceinline__ float gelu_f(float x) {
  float u = 1.5957691216057308f * (x + 0.044715f * x * x * x);
  return x / (1.f + __expf(-u));
}

// Routing with 256-aligned padded slot space. tiles[j] = (expert, s0) with
// s0 % 256 == 0; rows[] filled for ALL padded slots (pads duplicate the
// expert's first slot -> always-valid token ids). ends[e] = last real slot+1.
__global__ void route_kernel(const int* __restrict__ gidx,
                             int* __restrict__ rows,
                             int* __restrict__ ends,     // [E_+1]; [E_]=total
                             int2* __restrict__ tiles) {
  __shared__ int cnt[E_], base[E_], cur[E_];
  int tid = threadIdx.x;
  if (tid < E_) cnt[tid] = 0;
  __syncthreads();
  for (int p = tid; p < NP_; p += 256) atomicAdd(&cnt[gidx[p]], 1);
  __syncthreads();
  if (tid == 0) {
    int acc = 0, k = 0;
    int2 tmp[MTS_];
    for (int e = 0; e < E_; ++e) {
      base[e] = acc; cur[e] = acc;
      int nt = (cnt[e] + 255) >> 8;
      for (int m = 0; m < nt; ++m) tmp[k++] = make_int2(e, acc + m * 256);
      ends[e] = acc + cnt[e];
      acc += nt * 256;
    }
    ends[E_] = acc;
    // stride-7 scatter (coprime 32) for per-CU heavy-tile balance
    for (int j = 0; j < MTS_; ++j)
      tiles[(j * 7) & 31] = (j < k) ? tmp[j] : make_int2(-1, 0);
  }
  __syncthreads();
  for (int p = tid; p < NP_; p += 256) {
    int e = gidx[p];
    rows[atomicAdd(&cur[e], 1)] = p;
  }
  __syncthreads();
  for (int e = 0; e < E_; ++e) {
    int st = base[e] + cnt[e];
    int en = base[e] + (((cnt[e] + 255) >> 8) << 8);
    if (st >= en) continue;
    int fill = rows[base[e]];
    for (int s = st + tid; s < en; s += 256) rows[s] = fill;
  }
}

// Acts -> fragment layout per slot-group: xs[sg][kq=128][row=16][8].
// Reads inp linearly per token row (32B/thread contiguous runs); writes are
// L2-absorbed. One block per slot-group.
__global__ void xshuffle(const float* __restrict__ inp,
                         const int* __restrict__ rows,
                         const int* __restrict__ ends,
                         unsigned short* __restrict__ xs) {
  int sg = blockIdx.x;
  if (sg * 16 >= ends[E_]) return;
  __shared__ int tok[16];
  int t = threadIdx.x;
  if (t < 16) tok[t] = rows[sg * 16 + t] >> 1;   // pair -> token (K_=2)
  __syncthreads();
  unsigned short* dst = xs + (size_t)sg * 16384;
#pragma unroll
  for (int it = 0; it < 8; ++it) {
    int idx = it * 256 + t;            // [0, 2048)
    int r = idx >> 7, kq = idx & 127;
    const float* s = inp + (size_t)tok[r] * D_ + kq * 8;
    float4 v0 = *reinterpret_cast<const float4*>(s);
    float4 v1 = *reinterpret_cast<const float4*>(s + 4);
    short8 o;
    o[0]=(short)f2bf(v0.x); o[1]=(short)f2bf(v0.y);
    o[2]=(short)f2bf(v0.z); o[3]=(short)f2bf(v0.w);
    o[4]=(short)f2bf(v1.x); o[5]=(short)f2bf(v1.y);
    o[6]=(short)f2bf(v1.z); o[7]=(short)f2bf(v1.w);
    *reinterpret_cast<short8*>(dst + (size_t)kq * 128 + r * 8) = o;
  }
}

// W (f32 [E][N][K]) -> bf16 Wt fragment layout [e][n/16][k/32][plane=4][16][8]
// via LDS bounce: LINEAR global read -> LDS transpose -> LINEAR global write.
// Block handles 16 n-rows x 1024 k (w2 splits k into 2 halves).
__global__ __launch_bounds__(256)
void shuffle_w(const float* __restrict__ w1, const float* __restrict__ w2,
               unsigned short* __restrict__ wt1, unsigned short* __restrict__ wt2) {
  __shared__ unsigned short tmp[16][1028];   // +4 pad: bank stride 514 dw
  int bid = blockIdx.x;
  const float* src; unsigned short* dst; int rowstride;
  if (bid < 2048) {                      // w1: e in [0,16), g in [0,128)
    int e = bid >> 7, g = bid & 127;
    src = w1 + ((size_t)(e * 2048 + g * 16)) * 1024;
    dst = wt1 + ((size_t)(e * 128 + g) * 32) * 512;
    rowstride = 1024;
  } else {                               // w2: e, g in [0,64), ksblk in {0,1}
    int idx = bid - 2048;
    int e = idx >> 7, r2 = idx & 127, g = r2 >> 1, ksblk = r2 & 1;
    src = w2 + ((size_t)(e * 1024 + g * 16)) * 2048 + ksblk * 1024;
    dst = wt2 + ((size_t)((e * 64 + g) * 64 + ksblk * 32)) * 512;
    rowstride = 2048;
  }
  const int t = threadIdx.x;
#pragma unroll
  for (int it = 0; it < 16; ++it) {      // 16 rows x 1024 f32, linear read
    int off = (it * 256 + t) * 4;
    int r = off >> 10, k = off & 1023;
    float4 v = *reinterpret_cast<const float4*>(src + (size_t)r * rowstride + k);
    ushort4 u = make_ushort4(f2bf(v.x), f2bf(v.y), f2bf(v.z), f2bf(v.w));
    *reinterpret_cast<ushort4*>(&tmp[r][k]) = u;
  }
  __syncthreads();
#pragma unroll
  for (int it = 0; it < 8; ++it) {       // 2048 pieces, dst-linear write
    int j = it * 256 + t;
    int ks = j >> 6, jp = j & 63;
    int plane = jp >> 4, r = jp & 15;
    short8 v = *reinterpret_cast<const short8*>(&tmp[r][ks * 32 + plane * 8]);
    *reinterpret_cast<short8*>(dst + (size_t)j * 8) = v;
  }
}

// Flat GEMM over one (expert, 256-slot, 32-wrow) tile. 4 waves split slots
// (64 each); all operands are LINEAR bf16 streams (cell = ks*512 + lane*8).
// D map (m89): col = lane&15 = token row of B-frag; row = fh*4 + reg.
template<bool IS1>
__global__ __launch_bounds__(256, 3)
void moe_flat(const unsigned short* __restrict__ Act,   // xs (IS1) or hs
              const unsigned short* __restrict__ Wt,    // wt1 or wt2
              const float* __restrict__ bias,           // [E][NN]
              const int* __restrict__ rows,
              const int* __restrict__ ends,
              const int2* __restrict__ tiles,
              const float* __restrict__ score,          // [T*K]
              unsigned short* __restrict__ Hs,          // h fragment (IS1)
              float* __restrict__ Yout)                 // y (!IS1)
{
  constexpr int KS  = IS1 ? 32 : 64;          // K/32
  constexpr int NN  = IS1 ? H_ : D_;
  constexpr int NGw = NN / 16;
  constexpr int ASG = IS1 ? 16384 : 32768;    // act shorts per slot-group

  const int2 tile = tiles[blockIdx.y];
  const int e = tile.x;
  if (e < 0) return;
  const int s0 = tile.y;                      // 256-aligned

  const int tid = threadIdx.x, lane = tid & 63, wid = tid >> 6;
  const int fr = lane & 15, fh = lane >> 4;

  const int ng0 = blockIdx.x * 2;
  const unsigned short* wp0 = Wt + ((size_t)(e * NGw + ng0)) * KS * 512 + lane * 8;
  const unsigned short* wp1 = wp0 + (size_t)KS * 512;

  const int sgb = (s0 >> 4) + wid * 4;
  const unsigned short* ap[4];
#pragma unroll
  for (int g = 0; g < 4; ++g) ap[g] = Act + (size_t)(sgb + g) * ASG + lane * 8;

  f32x4 acc[4][2] = {};
  short8 w0[2], w1r[2], a0[4], a1[4];

  auto load = [&](short8* w, short8* a, int ks) {
    w[0] = *reinterpret_cast<const short8*>(wp0 + (size_t)ks * 512);
    w[1] = *reinterpret_cast<const short8*>(wp1 + (size_t)ks * 512);
#pragma unroll
    for (int g = 0; g < 4; ++g)
      a[g] = *reinterpret_cast<const short8*>(ap[g] + (size_t)ks * 512);
  };
  auto step = [&](short8* w, short8* a) {
#pragma unroll
    for (int g = 0; g < 4; ++g)
#pragma unroll
      for (int i = 0; i < 2; ++i)
        acc[g][i] = __builtin_amdgcn_mfma_f32_16x16x32_bf16(
            w[i], a[g], acc[g][i], 0, 0, 0);
  };

  load(w0, a0, 0);
  load(w1r, a1, 1);
  for (int t = 0; t < KS; t += 2) {
    step(w0, a0);
    if (t + 2 < KS) load(w0, a0, t + 2);
    step(w1r, a1);
    if (t + 3 < KS) load(w1r, a1, t + 3);
  }

  const int nb = blockIdx.x * 32;
  if (IS1) {
    // Write h DIRECTLY in fragment layout: hs[sg][kq=hcol>>3][fr][hcol&7].
    // Lane (fr,fh) holds hcols cb..cb+3 for token-slot sg*16+fr; pads too.
#pragma unroll
    for (int i = 0; i < 2; ++i) {
      int cb = nb + i * 16 + fh * 4;
      int kq = cb >> 3;                        // = (nb+i*16)>>3 + (fh>>1)
      float4 bs = *reinterpret_cast<const float4*>(bias + (size_t)e * NN + cb);
#pragma unroll
      for (int g = 0; g < 4; ++g) {
        int sg = sgb + g;
        ushort4 hv;
        hv.x = f2bf(gelu_f(acc[g][i][0] + bs.x));
        hv.y = f2bf(gelu_f(acc[g][i][1] + bs.y));
        hv.z = f2bf(gelu_f(acc[g][i][2] + bs.z));
        hv.w = f2bf(gelu_f(acc[g][i][3] + bs.w));
        *reinterpret_cast<ushort4*>(
            Hs + (((size_t)sg * 256 + kq) * 16 + fr) * 8 + (fh & 1) * 4) = hv;
      }
    }
  } else {
    const int send = ends[e];
#pragma unroll
    for (int i = 0; i < 2; ++i) {
      int cb = nb + i * 16 + fh * 4;
      float4 bs = *reinterpret_cast<const float4*>(bias + (size_t)e * NN + cb);
#pragma unroll
      for (int g = 0; g < 4; ++g) {
        int slot = s0 + wid * 64 + g * 16 + fr;
        if (slot >= send) continue;
        int pair = rows[slot];
        float sc = score[pair];
        float4 yv;
        yv.x = (acc[g][i][0] + bs.x) * sc;
        yv.y = (acc[g][i][1] + bs.y) * sc;
        yv.z = (acc[g][i][2] + bs.z) * sc;
        yv.w = (acc[g][i][3] + bs.w) * sc;
        *reinterpret_cast<float4*>(Yout + (size_t)pair * D_ + cb) = yv;
      }
    }
  }
}

__global__ void combine_kernel(const float* __restrict__ y,
                               float* __restrict__ out) {
  const int DQ = D_ / 4;
  int i = blockIdx.x * blockDim.x + threadIdx.x;   // [0, T_*D_/4)
  int t = i / DQ, d = i % DQ;
  const float4* y4 = reinterpret_cast<const float4*>(y);
  float4 a = y4[(size_t)(2 * t) * DQ + d];
  float4 b = y4[(size_t)(2 * t + 1) * DQ + d];
  reinterpret_cast<float4*>(out)[i] =
      make_float4(a.x + b.x, a.y + b.y, a.z + b.z, a.w + b.w);
}

extern "C" void kernel_launch(void* const* d_in, const int* in_sizes, int n_in,
                              void* d_out, int out_size, void* d_ws, size_t ws_size,
                              hipStream_t stream) {
  const float* inp    = (const float*)d_in[0];
  const int*   gidx   = (const int*)d_in[1];
  const float* gscore = (const float*)d_in[2];
  const float* w1     = (const float*)d_in[3];
  const float* b1     = (const float*)d_in[4];
  const float* w2     = (const float*)d_in[5];
  const float* b2     = (const float*)d_in[6];
  float* out = (float*)d_out;

  char* ws = (char*)d_ws;
  size_t o = 0;
  auto alloc = [&](size_t bytes) {
    void* p = ws + o;
    o = (o + bytes + 255) & ~(size_t)255;
    return p;
  };
  unsigned short* wt1 = (unsigned short*)alloc((size_t)E_ * H_ * D_ * 2);
  unsigned short* wt2 = (unsigned short*)alloc((size_t)E_ * D_ * H_ * 2);
  unsigned short* xs  = (unsigned short*)alloc((size_t)SGMAX_ * 16384 * 2);
  unsigned short* hs  = (unsigned short*)alloc((size_t)SGMAX_ * 32768 * 2);
  float*         ybuf = (float*)alloc((size_t)NP_ * D_ * 4);
  int*           rows = (int*)alloc((size_t)SGMAX_ * 16 * 4);
  int*           ends = (int*)alloc((E_ + 1) * 4);
  int2*         tiles = (int2*)alloc(MTS_ * 8);

  route_kernel<<<dim3(1), dim3(256), 0, stream>>>(gidx, rows, ends, tiles);
  xshuffle<<<dim3(SGMAX_), dim3(256), 0, stream>>>(inp, rows, ends, xs);
  shuffle_w<<<dim3(4096), dim3(256), 0, stream>>>(w1, w2, wt1, wt2);

  moe_flat<true><<<dim3(H_ / 32, MTS_), dim3(256), 0, stream>>>(
      xs, wt1, b1, rows, ends, tiles, gscore, hs, (float*)nullptr);
  moe_flat<false><<<dim3(D_ / 32, MTS_), dim3(256), 0, stream>>>(
      hs, wt2, b2, rows, ends, tiles, gscore, (unsigned short*)nullptr, ybuf);

  combine_kernel<<<dim3(T_ * D_ / 4 / 256), dim3(256), 0, stream>>>(ybuf, out);
}

// Round 11
// 186.376 us; speedup vs baseline: 1.3680x; 1.3680x over previous
//
#include <hip/hip_runtime.h>
#include <hip/hip_bf16.h>
#include <stdint.h>

// MoE (E=16, D=1024, H=2048, K=2, T=2048), routed bf16-MFMA.
// R11 = R9 pipeline with BK=32 and small LDS for 5-6 blocks/CU occupancy.
// A: global_load_lds, source swizzle slot^((row>>1)&3) -> conflict-free
//    (2-way only) reads at 64B row stride. 2 instrs/wave/step.
// B: f32 reg-staged (full-line loads), cvt bf16, ds_write into [BN][40]
//    (+8 pad: stride-20-dword -> all 8 bank groups, conflict-free, no swz).
// Counted vmcnt(NV) waits, NV = vmem-ops/step = 4 (GEMM1) / 3 (GEMM2).

#define E_ 16
#define D_ 1024
#define H_ 2048
#define K_ 2
#define T_ 2048
#define NP_ (T_ * K_)     // 4096 token-expert pairs
#define MTS_ 48           // max M-tiles: sum ceil(ne/128) <= 48

using short8 = __attribute__((ext_vector_type(8))) short;
using f32x4  = __attribute__((ext_vector_type(4))) float;

__device__ __forceinline__ unsigned short f2bf(float f) {
  union { float f; unsigned u; } x; x.f = f;
  unsigned r = x.u + 0x7fffu + ((x.u >> 16) & 1u);   // RNE
  return (unsigned short)(r >> 16);
}

// gelu(tanh approx) = x * sigmoid(1.595769...*(x + 0.044715 x^3))
__device__ __forceinline__ float gelu_f(float x) {
  float u = 1.5957691216057308f * (x + 0.044715f * x * x * x);
  return x / (1.f + __expf(-u));
}

__device__ __forceinline__ void waitv4() {
  asm volatile("s_waitcnt vmcnt(4)" ::: "memory");
  __builtin_amdgcn_sched_barrier(0);
}
__device__ __forceinline__ void waitv3() {
  asm volatile("s_waitcnt vmcnt(3)" ::: "memory");
  __builtin_amdgcn_sched_barrier(0);
}
__device__ __forceinline__ void waitv0() {
  asm volatile("s_waitcnt vmcnt(0)" ::: "memory");
  __builtin_amdgcn_sched_barrier(0);
}
__device__ __forceinline__ void barrier_only() {
  __builtin_amdgcn_sched_barrier(0);
  __builtin_amdgcn_s_barrier();
  __builtin_amdgcn_sched_barrier(0);
}
__device__ __forceinline__ void lgkm0_barrier() {
  asm volatile("s_waitcnt lgkmcnt(0)" ::: "memory");
  __builtin_amdgcn_sched_barrier(0);
  __builtin_amdgcn_s_barrier();
  __builtin_amdgcn_sched_barrier(0);
}

__global__ void cvt_kernel(const float* __restrict__ src,
                           unsigned short* __restrict__ dst, int n4) {
  int stride = gridDim.x * blockDim.x;
  for (int i = blockIdx.x * blockDim.x + threadIdx.x; i < n4; i += stride) {
    float4 v = reinterpret_cast<const float4*>(src)[i];
    ushort4 o = make_ushort4(f2bf(v.x), f2bf(v.y), f2bf(v.z), f2bf(v.w));
    reinterpret_cast<ushort4*>(dst)[i] = o;
  }
}

__global__ void route_kernel(const int* __restrict__ gidx,
                             int* __restrict__ rows,
                             int* __restrict__ offsets,
                             int2* __restrict__ tiles) {
  __shared__ int cnt[E_], cur[E_];
  int tid = threadIdx.x;
  if (tid < E_) cnt[tid] = 0;
  __syncthreads();
  for (int p = tid; p < NP_; p += blockDim.x) atomicAdd(&cnt[gidx[p]], 1);
  __syncthreads();
  if (tid == 0) {
    int acc = 0;
    for (int e = 0; e < E_; ++e) { offsets[e] = acc; cur[e] = acc; acc += cnt[e]; }
    offsets[E_] = acc;
    int k = 0;
    for (int e = 0; e < E_; ++e)
      for (int m = offsets[e]; m < offsets[e] + cnt[e]; m += 128)
        tiles[k++] = make_int2(e, m);
    for (; k < MTS_; ++k) tiles[k] = make_int2(-1, 0);
  }
  __syncthreads();
  for (int p = tid; p < NP_; p += blockDim.x) {
    int e = gidx[p];
    int pos = atomicAdd(&cur[e], 1);
    rows[pos] = p;
  }
}

#define GLOAD16(g, l)                                                        \
  __builtin_amdgcn_global_load_lds(                                          \
      (const __attribute__((address_space(1))) unsigned int*)(const void*)(g), \
      (__attribute__((address_space(3))) unsigned int*)(void*)(l), 16, 0, 0)

// NT GEMM: 128(M) x BN x 32(K) tile, 4 waves as 2x2.
template<bool IS1>
__global__ __launch_bounds__(256, IS1 ? 5 : 6)
void moe_gemm(const unsigned short* __restrict__ A0,   // xb (IS1) or h
              const float* __restrict__ W,             // w1 or w2 (f32)
              const float* __restrict__ bias,          // b1 or b2  [E][NN]
              const int* __restrict__ rows,
              const int* __restrict__ offsets,
              const int2* __restrict__ tiles,
              const float* __restrict__ score,         // [T*K]
              unsigned short* __restrict__ Hout,       // h (IS1)
              float* __restrict__ Yout)                // y (!IS1)
{
  constexpr int BM = 128, BK = 32;
  constexpr int BN = IS1 ? 64 : 32;
  constexpr int NI = BN / 32;         // B fragments per wave (2 or 1)
  constexpr int WN = BN / 2;          // wave n-extent
  constexpr int KD = IS1 ? D_ : H_;   // contraction dim
  constexpr int NN = IS1 ? H_ : D_;   // output cols
  constexpr int NT = KD / BK;         // 32 or 64 (even)

  const int2 tile = tiles[blockIdx.y];
  const int e = tile.x;
  if (e < 0) return;
  const int s0   = tile.y;
  const int send = offsets[e + 1];
  const int n0   = blockIdx.x * BN;

  __shared__ unsigned short As[2][BM][BK];       // A-swizzled (see below)
  __shared__ unsigned short Bs[2][BN][BK + 8];   // +8 pad: conflict-free
  __shared__ int rowsrc[BM];
  __shared__ int rowdst[BM];

  const int tid  = threadIdx.x;
  const int lane = tid & 63;
  const int wid  = tid >> 6;

  if (tid < BM) {
    int s = s0 + tid;
    bool v = s < send;
    int sc2 = v ? s : s0;
    if (IS1) {
      rowsrc[tid] = rows[sc2] >> 1;   // token id (K_=2)
      rowdst[tid] = v ? s : -1;       // h row (routed order)
    } else {
      rowsrc[tid] = sc2;              // h row
      rowdst[tid] = v ? rows[s] : -1; // pair id for scatter + score
    }
  }
  __syncthreads();

  // A staging: 2 x global_load_lds(16B)/wave, each = 16 rows x 64B.
  // LDS dest linear; SOURCE octet pre-XOR'd with (row>>1)&3 so that reads
  // (slot = fh ^ ((row>>1)&3)) are bank-conflict-free at 64B row stride.
  const int arow16 = lane >> 2;                  // 0..15
  const int aslot  = (lane & 3) ^ ((arow16 >> 1) & 3);
  const unsigned short* gA[2];
#pragma unroll
  for (int i = 0; i < 2; ++i)
    gA[i] = A0 + (size_t)rowsrc[wid * 32 + i * 16 + arow16] * KD + aslot * 8;

  // B staging, line-efficient: thread t -> row t>>3 (0..31), oct t&7.
  // Each wave-instr = 8 rows x 128B (full lines). IS1 adds rows +32.
  const int brow = tid >> 3, boct = tid & 7;
  const float* gB0 = W + (size_t)e * NN * KD + (size_t)(n0 + brow) * KD + boct * 4;
  const float* gB2 = gB0 + (size_t)32 * KD;      // used when BN=64

  const int wr = wid >> 1, wc = wid & 1;
  const int fr = lane & 15, fh = lane >> 4;

  f32x4 acc[4][NI] = {};
  float4 breg0[2], breg1[2];

  auto issueA = [&](int buf, int kk) {
#pragma unroll
    for (int i = 0; i < 2; ++i)
      GLOAD16(gA[i] + kk, &As[buf][wid * 32 + i * 16][0]);
  };
  auto issueB = [&](float4* br, int kk) {
    br[0] = *reinterpret_cast<const float4*>(gB0 + kk);
    if (IS1) br[1] = *reinterpret_cast<const float4*>(gB2 + kk);
  };
  auto writeB = [&](int buf, const float4* br) {
#pragma unroll
    for (int p = 0; p < (IS1 ? 2 : 1); ++p) {
      int row = brow + p * 32;
      ushort4 u;
      const float* f = &br[p].x;
      u.x = f2bf(f[0]); u.y = f2bf(f[1]); u.z = f2bf(f[2]); u.w = f2bf(f[3]);
      *reinterpret_cast<ushort4*>(&Bs[buf][row][boct * 4]) = u;
    }
  };
  auto compute = [&](int buf) {
    short8 af[4], bv[NI];
#pragma unroll
    for (int mi = 0; mi < 4; ++mi) {
      const int row = wr * 64 + mi * 16 + fr;
      const int slot = fh ^ ((row >> 1) & 3);
      af[mi] = *reinterpret_cast<const short8*>(&As[buf][row][slot * 8]);
    }
#pragma unroll
    for (int ni = 0; ni < NI; ++ni) {
      const int row = wc * WN + ni * 16 + fr;
      bv[ni] = *reinterpret_cast<const short8*>(&Bs[buf][row][fh * 8]);
    }
#pragma unroll
    for (int mi = 0; mi < 4; ++mi)
#pragma unroll
      for (int ni = 0; ni < NI; ++ni)
        acc[mi][ni] = __builtin_amdgcn_mfma_f32_16x16x32_bf16(
            af[mi], bv[ni], acc[mi][ni], 0, 0, 0);
  };
  auto waitNV = [&]() { if (IS1) waitv4(); else waitv3(); };

  // Prologue: issue tiles 0,1 (2*NV vmem ops/wave), land tile 0.
  issueA(0, 0);       issueB(breg0, 0);
  issueA(1, BK);      issueB(breg1, BK);
  waitNV();                       // tile-0 ops complete
  writeB(0, breg0);
  lgkm0_barrier();                // all waves: tile 0 fully in LDS

  for (int t = 0; t < NT; t += 2) {
    // ---- step t (buffers 0) ----
    compute(0);
    barrier_only();               // all waves done reading LDS[0]
    if (t + 2 < NT) {
      issueA(0, (t + 2) * BK); issueB(breg0, (t + 2) * BK);
      waitNV();                   // {t+1} ops complete
    } else {
      waitv0();
    }
    writeB(1, breg1);
    lgkm0_barrier();              // all waves: tile t+1 fully in LDS
    // ---- step t+1 (buffers 1) ----
    compute(1);
    barrier_only();               // all waves done reading LDS[1]
    if (t + 2 < NT) {
      if (t + 3 < NT) { issueA(1, (t + 3) * BK); issueB(breg1, (t + 3) * BK); waitNV(); }
      else            { waitv0(); }
      writeB(0, breg0);
      lgkm0_barrier();            // all waves: tile t+2 fully in LDS
    }
  }

  // Epilogue. C/D map: row = (lane>>4)*4 + j, col = lane&15 (m89-verified).
  const float* biasE = bias + (size_t)e * NN + n0;
#pragma unroll
  for (int mi = 0; mi < 4; ++mi) {
#pragma unroll
    for (int j = 0; j < 4; ++j) {
      int rt  = wr * 64 + mi * 16 + fh * 4 + j;
      int dst = rowdst[rt];
      if (dst < 0) continue;
      float sc = IS1 ? 0.f : score[dst];
#pragma unroll
      for (int ni = 0; ni < NI; ++ni) {
        int col = wc * WN + ni * 16 + fr;
        float v = acc[mi][ni][j] + biasE[col];
        if (IS1) {
          Hout[(size_t)dst * H_ + n0 + col] = f2bf(gelu_f(v));
        } else {
          Yout[(size_t)dst * D_ + n0 + col] = v * sc;
        }
      }
    }
  }
}

__global__ void combine_kernel(const float* __restrict__ y,
                               float* __restrict__ out) {
  const int DQ = D_ / 4;
  int i = blockIdx.x * blockDim.x + threadIdx.x;   // [0, T_*D_/4)
  int t = i / DQ, d = i % DQ;
  const float4* y4 = reinterpret_cast<const float4*>(y);
  float4 a = y4[(size_t)(2 * t) * DQ + d];
  float4 b = y4[(size_t)(2 * t + 1) * DQ + d];
  reinterpret_cast<float4*>(out)[i] =
      make_float4(a.x + b.x, a.y + b.y, a.z + b.z, a.w + b.w);
}

extern "C" void kernel_launch(void* const* d_in, const int* in_sizes, int n_in,
                              void* d_out, int out_size, void* d_ws, size_t ws_size,
                              hipStream_t stream) {
  const float* inp    = (const float*)d_in[0];
  const int*   gidx   = (const int*)d_in[1];
  const float* gscore = (const float*)d_in[2];
  const float* w1     = (const float*)d_in[3];
  const float* b1     = (const float*)d_in[4];
  const float* w2     = (const float*)d_in[5];
  const float* b2     = (const float*)d_in[6];
  float* out = (float*)d_out;

  char* ws = (char*)d_ws;
  size_t o = 0;
  auto alloc = [&](size_t bytes) {
    void* p = ws + o;
    o = (o + bytes + 255) & ~(size_t)255;
    return p;
  };
  unsigned short* xb   = (unsigned short*)alloc((size_t)T_ * D_ * 2);
  unsigned short* hbuf = (unsigned short*)alloc((size_t)NP_ * H_ * 2);
  float*          ybuf = (float*)alloc((size_t)NP_ * D_ * 4);
  int*            rows = (int*)alloc(NP_ * 4);
  int*         offsets = (int*)alloc((E_ + 1) * 4);
  int2*          tiles = (int2*)alloc(MTS_ * 8);

  cvt_kernel<<<dim3(512), dim3(256), 0, stream>>>(inp, xb, T_ * D_ / 4);
  route_kernel<<<dim3(1), dim3(256), 0, stream>>>(gidx, rows, offsets, tiles);

  moe_gemm<true><<<dim3(H_ / 64, MTS_), dim3(256), 0, stream>>>(
      xb, w1, b1, rows, offsets, tiles, gscore, hbuf, (float*)nullptr);
  moe_gemm<false><<<dim3(D_ / 32, MTS_), dim3(256), 0, stream>>>(
      hbuf, w2, b2, rows, offsets, tiles, gscore, (unsigned short*)nullptr, ybuf);

  combine_kernel<<<dim3(T_ * D_ / 4 / 256), dim3(256), 0, stream>>>(ybuf, out);
}